// Round 13
// baseline (78.141 us; speedup 1.0000x reference)
//
#include <hip/hip_runtime.h>
#include <math.h>

#define DIM 128

typedef __attribute__((ext_vector_type(8))) _Float16 f16x8;
typedef __attribute__((ext_vector_type(4))) float f32x4;

static __device__ __forceinline__ unsigned short f2h(float v) {
  _Float16 hv = (_Float16)v;           // RNE f32->f16
  unsigned short u;
  __builtin_memcpy(&u, &hv, 2);
  return u;
}

// ---------------- Kernel 1: build U in MFMA fragment layout (f16) ---------
// frag(ct,kt): elem (lane,e) = Bl[n][k], n = ct*16+(lane&15),
// k = kt*32+(lane>>4)*8+e, Bl[n][k] = (n<128)? Re U[n][k] : Im U[n-128][k].
__global__ __launch_bounds__(256) void build_unitary_k(
    const float* __restrict__ qw, unsigned short* __restrict__ Bf) {
  __shared__ float gm[35][8];
  const int tid = threadIdx.x;

  if (tid < 35) {
    const float phi = qw[tid * 3 + 0];
    const float th  = qw[tid * 3 + 1];
    const float om  = qw[tid * 3 + 2];
    float sh, ch; sincosf(0.5f * th, &sh, &ch);
    const float a = 0.5f * (phi + om);
    const float b = 0.5f * (phi - om);
    float sa, ca; sincosf(a, &sa, &ca);
    float sb, cb; sincosf(b, &sb, &cb);
    gm[tid][0] =  ca * ch;  gm[tid][1] = -sa * ch;
    gm[tid][2] = -cb * sh;  gm[tid][3] = -sb * sh;
    gm[tid][4] =  cb * sh;  gm[tid][5] = -sb * sh;
    gm[tid][6] =  ca * ch;  gm[tid][7] =  sa * ch;
  }
  __syncthreads();

  const int lane = tid & 63;
  const int k    = blockIdx.x * 4 + (tid >> 6);

  float rl = (k == lane)      ? 1.f : 0.f;
  float rh = (k == lane + 64) ? 1.f : 0.f;
  float il = 0.f, ih = 0.f;

  for (int l = 0; l < 5; ++l) {
    const int r = l % 6 + 1;
    for (int q = 0; q < 7; ++q) {
      const float* g = gm[l * 7 + q];
      const float g0 = g[0], g1 = g[1], g2 = g[2], g3 = g[3];
      const float g4 = g[4], g5 = g[5], g6 = g[6], g7 = g[7];
      if (q == 0) {
        const float nrl = g0 * rl - g1 * il + g2 * rh - g3 * ih;
        const float nil = g0 * il + g1 * rl + g2 * ih + g3 * rh;
        const float nrh = g4 * rl - g5 * il + g6 * rh - g7 * ih;
        const float nih = g4 * il + g5 * rl + g6 * ih + g7 * rh;
        rl = nrl; il = nil; rh = nrh; ih = nih;
      } else {
        const int m = 1 << (6 - q);
        const int bit = (lane & m) ? 1 : 0;
        const float prl = __shfl_xor(rl, m), pil = __shfl_xor(il, m);
        const float prh = __shfl_xor(rh, m), pih = __shfl_xor(ih, m);
        const float udr = bit ? g6 : g0, udi = bit ? g7 : g1;
        const float uor = bit ? g4 : g2, uoi = bit ? g5 : g3;
        const float nrl = udr * rl - udi * il + uor * prl - uoi * pil;
        const float nil = udr * il + udi * rl + uor * pil + uoi * prl;
        const float nrh = udr * rh - udi * ih + uor * prh - uoi * pih;
        const float nih = udr * ih + udi * rh + uor * pih + uoi * prh;
        rl = nrl; il = nil; rh = nrh; ih = nih;
      }
    }
    for (int q = 0; q < 7; ++q) {
      const int tg = (q + r) % 7;
      if (q == 0) {
        const int mt = 1 << (6 - tg);
        const float prh = __shfl_xor(rh, mt), pih = __shfl_xor(ih, mt);
        rh = prh; ih = pih;
      } else if (tg == 0) {
        const int mc = 1 << (6 - q);
        const bool cb = (lane & mc) != 0;
        const float trl = cb ? rh : rl, til = cb ? ih : il;
        const float trh = cb ? rl : rh, tih = cb ? il : ih;
        rl = trl; il = til; rh = trh; ih = tih;
      } else {
        const int mc = 1 << (6 - q), mt = 1 << (6 - tg);
        const bool cb = (lane & mc) != 0;
        const float prl = __shfl_xor(rl, mt), pil = __shfl_xor(il, mt);
        const float prh = __shfl_xor(rh, mt), pih = __shfl_xor(ih, mt);
        rl = cb ? prl : rl; il = cb ? pil : il;
        rh = cb ? prh : rh; ih = cb ? pih : ih;
      }
    }
  }

  const int kt = k >> 5, kl = (k >> 3) & 3, e = k & 7;
  {
    const float vals[4] = {rl, rh, il, ih};
    #pragma unroll
    for (int t = 0; t < 4; ++t) {
      const int n = lane + t * 64;
      const int off = (((n >> 4) * 4 + kt) * 64 + kl * 16 + (n & 15)) * 8 + e;
      Bf[off] = f2h(vals[t]);
    }
  }
}

// ---------------- Kernel 2: f16 MFMA GEMM + cheap epilogue + MLP ----------
// Block: 512 thr = 8 waves, 64 samples. Wave w: A = U row-tiles {w (Re), w+8 (Im)}
// with rotated per-kt prefetch; B = S f16 frags in LDS. D: col = sample,
// row = u-sub-index. x staged coalesced through LDS.
__global__ __launch_bounds__(512, 4) void vqc_mlp_k(
    const float* __restrict__ x, const unsigned short* __restrict__ Bf,
    const float* __restrict__ W1, const float* __restrict__ b1,
    const float* __restrict__ W2, const float* __restrict__ b2,
    float* __restrict__ out) {
  __shared__ float smem[5632];                         // 22 KB
  unsigned short* Ahf = (unsigned short*)smem;         // 64*136 ushorts = floats [0,4352)
  float* qaP = smem;                                   // alias post-MFMA: [8][64][9]
  float* QA  = smem + 4608;                            // [64][8] floats [4608,5120)
  float* xs  = smem + 5120;                            // [448] staged x

  const int tid  = threadIdx.x;
  const int lane = tid & 63;
  const int w    = tid >> 6;
  const int s0   = blockIdx.x * 64;

  // ---- issue kt=0 B loads + coalesced x stage; both fly under S-build ----
  const f16x8* __restrict__ Bf8 = (const f16x8*)Bf;
  const int boff0 = (w * 4) * 64 + lane;          // ct0 = w      (Re rows)
  const int boff1 = ((w + 8) * 4) * 64 + lane;    // ct1 = w + 8  (Im rows)
  f16x8 b0 = Bf8[boff0];
  f16x8 b1v = Bf8[boff1];
  if (tid < 448) xs[tid] = x[s0 * 7 + tid];
  __syncthreads();

  // ---- S tile: product state -> f16 fragments (8 thr/sample, 16 k each) ----
  {
    const int sam = tid >> 3;       // 0..63
    const int ko  = tid & 7;        // k = ko*16 + j
    const float* xp = &xs[sam * 7];
    float cq[7], sq[7];
    #pragma unroll
    for (int q = 0; q < 7; ++q) __sincosf(0.5f * xp[q], &sq[q], &cq[q]);
    // k bits 6..4 = ko bits 2..0 (wires 0..2); k bits 3..0 = j (wires 3..6)
    float sv[16];
    sv[0] = ((ko & 4) ? sq[0] : cq[0]) * ((ko & 2) ? sq[1] : cq[1]) *
            ((ko & 1) ? sq[2] : cq[2]);
    #pragma unroll
    for (int q = 3; q < 7; ++q) {
      const int cnt = 1 << (q - 3);
      #pragma unroll
      for (int t2 = cnt - 1; t2 >= 0; --t2) {
        const float v = sv[t2];
        sv[2 * t2 + 1] = v * sq[q];
        sv[2 * t2]     = v * cq[q];
      }
    }
    f16x8 h8a, h8b;
    #pragma unroll
    for (int e = 0; e < 8; ++e) {
      h8a[e] = (_Float16)sv[e];
      h8b[e] = (_Float16)sv[8 + e];
    }
    *(f16x8*)&Ahf[sam * 136 + ko * 16]     = h8a;
    *(f16x8*)&Ahf[sam * 136 + ko * 16 + 8] = h8b;
  }
  __syncthreads();

  // ---- main loop: D[u-idx][sample]; 1-term f16, K=128, rotated prefetch ----
  f32x4 accR[4], accI[4];
  #pragma unroll
  for (int st = 0; st < 4; ++st) {
    accR[st] = (f32x4){0.f, 0.f, 0.f, 0.f};
    accI[st] = (f32x4){0.f, 0.f, 0.f, 0.f};
  }
  const int kloff = (lane >> 4) * 8;
  const int csub  = lane & 15;
  #pragma unroll
  for (int kt = 0; kt < 4; ++kt) {
    f16x8 nb0, nb1;
    if (kt < 3) {                       // prefetch kt+1 during kt's MFMAs
      nb0 = Bf8[boff0 + (kt + 1) * 64];
      nb1 = Bf8[boff1 + (kt + 1) * 64];
    }
    const int ko2 = kt * 32 + kloff;
    #pragma unroll
    for (int st = 0; st < 4; ++st) {
      const f16x8 ah = *(const f16x8*)&Ahf[(st * 16 + csub) * 136 + ko2];
      accR[st] = __builtin_amdgcn_mfma_f32_16x16x32_f16(b0, ah, accR[st], 0, 0, 0);
      accI[st] = __builtin_amdgcn_mfma_f32_16x16x32_f16(b1v, ah, accI[st], 0, 0, 0);
    }
    if (kt < 3) { b0 = nb0; b1v = nb1; }
  }

  // ---- epilogue: i = w*16 + (lane>>4)*4 + r. wires 5,6 <- r bits (in-lane);
  // wires 3,4 <- lane bits 5,4 (2 shfl stages); wires 0-2 <- w bits (signs) ----
  const int sg0 = (w >> 2) & 1, sg1 = (w >> 1) & 1, sg2 = w & 1;
  float qv7[4][7];
  #pragma unroll
  for (int st = 0; st < 4; ++st) {
    const f32x4 yr = accR[st];
    const f32x4 yi = accI[st];
    const float p0 = yr[0] * yr[0] + yi[0] * yi[0];
    const float p1 = yr[1] * yr[1] + yi[1] * yi[1];
    const float p2 = yr[2] * yr[2] + yi[2] * yi[2];
    const float p3 = yr[3] * yr[3] + yi[3] * yi[3];
    const float t  = p0 + p1 + p2 + p3;
    const float d5 = p0 + p1 - p2 - p3;   // wire5 <- i bit1
    const float d6 = p0 - p1 + p2 - p3;   // wire6 <- i bit0
    const float t16 = __shfl_xor(t, 16);
    const float a   = t + t16;
    const float b4  = (lane & 16) ? (t16 - t) : (t - t16);   // wire4 <- i bit2
    const float a32 = __shfl_xor(a, 32);
    const float T   = a + a32;
    const float D3  = (lane & 32) ? (a32 - a) : (a - a32);   // wire3 <- i bit3
    const float D4  = b4 + __shfl_xor(b4, 32);
    const float d5a = d5 + __shfl_xor(d5, 16);
    const float D5  = d5a + __shfl_xor(d5a, 32);
    const float d6a = d6 + __shfl_xor(d6, 16);
    const float D6  = d6a + __shfl_xor(d6a, 32);
    qv7[st][0] = sg0 ? -T : T;
    qv7[st][1] = sg1 ? -T : T;
    qv7[st][2] = sg2 ? -T : T;
    qv7[st][3] = D3; qv7[st][4] = D4; qv7[st][5] = D5; qv7[st][6] = D6;
  }
  __syncthreads();   // A-frag reads done; safe to alias qaP

  if (lane < 16) {
    #pragma unroll
    for (int st = 0; st < 4; ++st) {
      const int base = w * 576 + (st * 16 + lane) * 9;
      #pragma unroll
      for (int q = 0; q < 7; ++q) qaP[base + q] = qv7[st][q];
    }
  }
  __syncthreads();

  // ---- reduce over waves: thread (q = tid>>6, s = tid&63), q < 7 ----
  if (tid < 448) {
    const int q = tid >> 6, s = tid & 63;
    float acc = 0.f;
    #pragma unroll
    for (int wv = 0; wv < 8; ++wv) acc += qaP[wv * 576 + s * 9 + q];
    QA[s * 8 + q] = acc;
  }
  __syncthreads();

  // ---- MLP: thread (s = tid>>3, t8 = tid&7) emits logits t8, t8+8, t8+16 ----
  {
    const int s  = tid >> 3;
    const int t8 = tid & 7;
    float qv[7];
    #pragma unroll
    for (int q = 0; q < 7; ++q) qv[q] = QA[s * 8 + q];
    float h[16];
    #pragma unroll
    for (int k = 0; k < 16; ++k) {
      float a2 = b1[k];
      #pragma unroll
      for (int q = 0; q < 7; ++q) a2 += W1[k * 7 + q] * qv[q];
      h[k] = fmaxf(a2, 0.f);
    }
    #pragma unroll
    for (int oi = 0; oi < 3; ++oi) {
      const int o = t8 + oi * 8;
      if (o < 22) {
        float lg2 = b2[o];
        #pragma unroll
        for (int k = 0; k < 16; ++k) lg2 += W2[o * 16 + k] * h[k];
        out[(s0 + s) * 22 + o] = lg2;
      }
    }
  }
}

extern "C" void kernel_launch(void* const* d_in, const int* in_sizes, int n_in,
                              void* d_out, int out_size, void* d_ws, size_t ws_size,
                              hipStream_t stream) {
  const float* x  = (const float*)d_in[0];
  const float* qw = (const float*)d_in[1];
  const float* W1 = (const float*)d_in[2];
  const float* b1 = (const float*)d_in[3];
  const float* W2 = (const float*)d_in[4];
  const float* b2 = (const float*)d_in[5];
  float* out = (float*)d_out;
  unsigned short* Bf = (unsigned short*)d_ws;            // 64 KiB f16 U-frags

  const int B = in_sizes[0] / 7;

  build_unitary_k<<<32, 256, 0, stream>>>(qw, Bf);

  vqc_mlp_k<<<B / 64, 512, 0, stream>>>(x, Bf, W1, b1, W2, b2, out);
}